// Round 10
// baseline (391.607 us; speedup 1.0000x reference)
//
#include <hip/hip_runtime.h>
#include <math.h>

typedef unsigned int u32;
typedef unsigned short u16;

#define T_ 16
#define B_ 32
#define S_ 256
#define H_ 256
#define E_ 300
#define V_ 1000

__device__ __forceinline__ float fast_tanh(float x) {
    return 1.0f - 2.0f / (__expf(2.0f * x) + 1.0f);
}
__device__ __forceinline__ float fast_sigm(float x) {
    return 1.0f / (1.0f + __expf(-x));
}
__device__ __forceinline__ float bf2f(u16 x) { return __uint_as_float(((u32)x) << 16); }
__device__ __forceinline__ float blo(u32 u) { return __uint_as_float(u << 16); }
__device__ __forceinline__ float bhi(u32 u) { return __uint_as_float(u & 0xffff0000u); }
__device__ __forceinline__ u16 f2bf(float f) {
    u32 u = __float_as_uint(f);
    u32 r = (u + 0x7fffu + ((u >> 16) & 1u)) >> 16;
    return (u16)r;
}

// ---------------------------------------------------------------------------
// 128x128 GEMM tile body, 1024 threads, BK=32, 4x4/thread.
// C[M,N] = A[M,K] (opt row-gather) @ Bw[N,K]^T + bias.  Proven as the enc_t
// path in round 9 (4 waves/SIMD hides LDS latency; 256-thr/64x64 tiles do not).
// Guards: A-row gather + K tail (kb+4>K) + N guard on store.
// ---------------------------------------------------------------------------
__device__ __forceinline__
void gemm_tile_1024(const float* __restrict__ A, const int* __restrict__ gidx,
                    int lda, const float* __restrict__ Bw,
                    const float* __restrict__ bias, float* __restrict__ C,
                    int N, int K, int ldc, int bm, int bn,
                    float As2[32][132], float Bs2[32][132])
{
    const int tid = threadIdx.x;
    const int tx = tid & 31, ty = tid >> 5;   // 32x32 threads
    const int lr = tid >> 3;                  // 0..127
    const int lk = (tid & 7) * 4;             // 0,4,..,28

    int am = bm + lr;
    int arow = gidx ? gidx[am] : am;
    const float* Ap = A + (size_t)arow * lda;
    int bnr = bn + lr;
    const float* Bp = (bnr < N) ? (Bw + (size_t)bnr * K) : nullptr;
    float acc[4][4] = {};

    for (int k0 = 0; k0 < K; k0 += 32) {
        int kb = k0 + lk;
        float a0, a1, a2, a3, b0, b1, b2, b3;
        if (kb + 4 <= K) {
            float4 a4 = *(const float4*)(Ap + kb);
            a0 = a4.x; a1 = a4.y; a2 = a4.z; a3 = a4.w;
        } else {
            a0 = (kb + 0 < K) ? Ap[kb + 0] : 0.f;
            a1 = (kb + 1 < K) ? Ap[kb + 1] : 0.f;
            a2 = (kb + 2 < K) ? Ap[kb + 2] : 0.f;
            a3 = (kb + 3 < K) ? Ap[kb + 3] : 0.f;
        }
        if (Bp && kb + 4 <= K) {
            float4 b4 = *(const float4*)(Bp + kb);
            b0 = b4.x; b1 = b4.y; b2 = b4.z; b3 = b4.w;
        } else if (Bp) {
            b0 = (kb + 0 < K) ? Bp[kb + 0] : 0.f;
            b1 = (kb + 1 < K) ? Bp[kb + 1] : 0.f;
            b2 = (kb + 2 < K) ? Bp[kb + 2] : 0.f;
            b3 = (kb + 3 < K) ? Bp[kb + 3] : 0.f;
        } else {
            b0 = b1 = b2 = b3 = 0.f;
        }
        As2[lk + 0][lr] = a0; As2[lk + 1][lr] = a1;
        As2[lk + 2][lr] = a2; As2[lk + 3][lr] = a3;
        Bs2[lk + 0][lr] = b0; Bs2[lk + 1][lr] = b1;
        Bs2[lk + 2][lr] = b2; Bs2[lk + 3][lr] = b3;
        __syncthreads();
        #pragma unroll
        for (int kk = 0; kk < 32; kk++) {
            float4 a = *(const float4*)&As2[kk][ty * 4];
            float4 b = *(const float4*)&Bs2[kk][tx * 4];
            acc[0][0] += a.x*b.x; acc[0][1] += a.x*b.y; acc[0][2] += a.x*b.z; acc[0][3] += a.x*b.w;
            acc[1][0] += a.y*b.x; acc[1][1] += a.y*b.y; acc[1][2] += a.y*b.z; acc[1][3] += a.y*b.w;
            acc[2][0] += a.z*b.x; acc[2][1] += a.z*b.y; acc[2][2] += a.z*b.z; acc[2][3] += a.z*b.w;
            acc[3][0] += a.w*b.x; acc[3][1] += a.w*b.y; acc[3][2] += a.w*b.z; acc[3][3] += a.w*b.w;
        }
        __syncthreads();
    }
    #pragma unroll
    for (int i = 0; i < 4; i++) {
        int m = bm + ty * 4 + i;
        #pragma unroll
        for (int j = 0; j < 4; j++) {
            int n = bn + tx * 4 + j;
            if (n < N) C[(size_t)m * ldc + n] = acc[i][j] + bias[n];
        }
    }
}

// ---------------------------------------------------------------------------
// Kernel 1: prep — xproj GEMM (128x128 tiles) + Whh transpose(bf16) + Wd
// transpose(fp32). 1024 threads/block.
//   bid < 32         : xproj tile (M=512, N=1024, K=300, gather emb rows)
//   32 <= bid < 288  : Wt[k*1024+r] = bf16(Whh[r*256+k])
//   288 <= bid < 352 : Wdt[k*256+h] = Wd[h*256+k]
// ---------------------------------------------------------------------------
__global__ __launch_bounds__(1024, 4)
void prep_xproj(const float* __restrict__ emb, const int* __restrict__ tv,
                const float* __restrict__ W_ih, const float* __restrict__ b_ih,
                float* __restrict__ xproj,
                const float* __restrict__ Whh, u16* __restrict__ Wt,
                const float* __restrict__ Wd, float* __restrict__ Wdt)
{
    __shared__ float As2[32][132];
    __shared__ float Bs2[32][132];
    const int bid = blockIdx.x;
    if (bid < 32) {
        gemm_tile_1024(emb, tv, E_, W_ih, b_ih, xproj, 1024, E_, 1024,
                       (bid >> 3) * 128, (bid & 7) * 128, As2, Bs2);
    } else if (bid < 288) {
        int idx = (bid - 32) * 1024 + threadIdx.x;   // 0..262143
        int k = idx >> 10;
        int r = idx & 1023;
        Wt[idx] = f2bf(Whh[(size_t)r * 256 + k]);
    } else if (bid < 352) {
        int idx = (bid - 288) * 1024 + threadIdx.x;  // 0..65535
        int k = idx >> 8;
        int h = idx & 255;
        Wdt[idx] = Wd[(size_t)h * 256 + k];
    }
}

// ---------------------------------------------------------------------------
// Kernel 2: heterogeneous lstm + enc_t. 1024 threads/block, grid = 32+128.
//   bid < 32 : LSTM scan — uint2 W loads (4 bf16/lane, half the VMEM issue of
//              round-8's u32), acc[4], #pragma unroll 2 caps the load cluster
//              at 8 in flight (live ~46 VGPR: no spill; rounds 6/7 lesson).
//   bid >= 32: enc_t 128x128 tile (M=8192, N=256, K=256) on idle CUs.
// ---------------------------------------------------------------------------
__global__ __launch_bounds__(1024, 4)
void lstm_enct(const float* __restrict__ xproj,   // [T,B,1024]
               const u16*   __restrict__ Wt,      // [256,1024] bf16
               const float* __restrict__ bhh,     // [1024]
               const float* __restrict__ h0, const float* __restrict__ c0,
               float* __restrict__ combined,      // [T,B,512] second half
               float* __restrict__ hT, float* __restrict__ cT,
               const float* __restrict__ enc_raw, // [8192,256]
               const float* __restrict__ We,      // [256,256]
               const float* __restrict__ be,
               float* __restrict__ enct)          // [8192,256]
{
    const int bid = blockIdx.x;
    const int tid = threadIdx.x;
    __shared__ float hs[256], cs[256];
    __shared__ float zp[4][1024];
    __shared__ float As2[32][132];
    __shared__ float Bs2[32][132];

    if (bid < 32) {
        // ----- LSTM path -----
        const int b  = bid;
        const int kg = tid >> 8;          // 0..3, k-slice of 64
        const int rq = tid & 255;         // r-quad
        const int r0 = rq * 4;
        if (tid < 256) {
            hs[tid] = h0[b * 256 + tid];
            cs[tid] = c0[b * 256 + tid];
        }
        const float bh = bhh[tid];
        const u16* wbase = Wt + (size_t)(kg * 64) * 1024 + r0;
        __syncthreads();

        for (int t = 0; t < T_; t++) {
            float a0 = 0.f, a1 = 0.f, a2 = 0.f, a3 = 0.f;
            #pragma unroll 2
            for (int kk = 0; kk < 64; kk += 4) {
                float4 h4 = *(const float4*)&hs[kg * 64 + kk];
                uint2 wA = *(const uint2*)(wbase + (size_t)(kk + 0) * 1024);
                uint2 wB = *(const uint2*)(wbase + (size_t)(kk + 1) * 1024);
                uint2 wC = *(const uint2*)(wbase + (size_t)(kk + 2) * 1024);
                uint2 wD = *(const uint2*)(wbase + (size_t)(kk + 3) * 1024);
                a0 += blo(wA.x)*h4.x; a1 += bhi(wA.x)*h4.x;
                a2 += blo(wA.y)*h4.x; a3 += bhi(wA.y)*h4.x;
                a0 += blo(wB.x)*h4.y; a1 += bhi(wB.x)*h4.y;
                a2 += blo(wB.y)*h4.y; a3 += bhi(wB.y)*h4.y;
                a0 += blo(wC.x)*h4.z; a1 += bhi(wC.x)*h4.z;
                a2 += blo(wC.y)*h4.z; a3 += bhi(wC.y)*h4.z;
                a0 += blo(wD.x)*h4.w; a1 += bhi(wD.x)*h4.w;
                a2 += blo(wD.y)*h4.w; a3 += bhi(wD.y)*h4.w;
            }
            *(float4*)&zp[kg][r0] = make_float4(a0, a1, a2, a3);
            __syncthreads();

            float z = xproj[((size_t)t * B_ + b) * 1024 + tid] + bh
                    + zp[0][tid] + zp[1][tid] + zp[2][tid] + zp[3][tid];
            __syncthreads();
            zp[0][tid] = z;
            __syncthreads();

            if (tid < 256) {
                float ig = fast_sigm(zp[0][tid]);
                float fg = fast_sigm(zp[0][256 + tid]);
                float gg = fast_tanh(zp[0][512 + tid]);
                float og = fast_sigm(zp[0][768 + tid]);
                float c = fg * cs[tid] + ig * gg;
                float h = og * fast_tanh(c);
                cs[tid] = c;
                hs[tid] = h;
                combined[((size_t)t * B_ + b) * 512 + 256 + tid] = h;
                if (t == T_ - 1) {
                    hT[b * 256 + tid] = h;
                    cT[b * 256 + tid] = c;
                }
            }
            __syncthreads();
        }
    } else {
        // ----- enc_t path -----
        const int tile = bid - 32;
        gemm_tile_1024(enc_raw, nullptr, 256, We, be, enct, 256, 256, 256,
                       (tile >> 1) * 128, (tile & 1) * 128, As2, Bs2);
    }
}

// ---------------------------------------------------------------------------
// Kernel 3: attention with inlined dec_t row. Block per (b,t), 256 threads.
// ---------------------------------------------------------------------------
__global__ __launch_bounds__(256)
void attn2(const float* __restrict__ enct,     // [S,B,H]
           const float* __restrict__ combined_in, // [T,B,512] (2nd half = out)
           const float* __restrict__ Wdt,      // [256,256] k-major
           const float* __restrict__ bd,
           const float* __restrict__ enc_raw,  // [S,B,H]
           const float* __restrict__ wa, const float* __restrict__ ba,
           const int* __restrict__ lens,
           float* __restrict__ ctx_out,        // [B,T,H] (d_out)
           float* __restrict__ combined_out)   // [T,B,512] first half
{
    const int bid = blockIdx.x;
    const int b = bid >> 4;
    const int t = bid & 15;
    const int tid = threadIdx.x;
    __shared__ float outs[256], ds[256], was[256], sc[256];
    __shared__ float red[8];

    outs[tid] = combined_in[((size_t)t * B_ + b) * 512 + 256 + tid];
    was[tid]  = wa[tid];
    const int len = lens[b];
    const float bav = ba[0];
    __syncthreads();

    {
        float acc = bd[tid];
        const float* wp = Wdt + tid;
        #pragma unroll 4
        for (int k = 0; k < 256; k++) acc += wp[(size_t)k * 256] * outs[k];
        ds[tid] = acc;
    }
    __syncthreads();

    const int wv = tid >> 6, lane = tid & 63;
    for (int s = wv; s < len; s += 4) {
        const float* er = enct + ((size_t)s * B_ + b) * 256;
        float sum = 0.0f;
        #pragma unroll
        for (int j = 0; j < 4; j++) {
            int h = lane + 64 * j;
            sum += fast_tanh(er[h] + ds[h]) * was[h];
        }
        #pragma unroll
        for (int off = 32; off >= 1; off >>= 1) sum += __shfl_xor(sum, off, 64);
        if (lane == 0) sc[s] = sum + bav;
    }
    __syncthreads();

    float x = (tid < len) ? sc[tid] : -INFINITY;
    float m = x;
    #pragma unroll
    for (int off = 32; off >= 1; off >>= 1) m = fmaxf(m, __shfl_xor(m, off, 64));
    if (lane == 0) red[wv] = m;
    __syncthreads();
    m = fmaxf(fmaxf(red[0], red[1]), fmaxf(red[2], red[3]));
    float e = __expf(x - m);
    float ssum = e;
    #pragma unroll
    for (int off = 32; off >= 1; off >>= 1) ssum += __shfl_xor(ssum, off, 64);
    if (lane == 0) red[4 + wv] = ssum;
    __syncthreads();
    ssum = red[4] + red[5] + red[6] + red[7];
    __syncthreads();
    sc[tid] = e / ssum;
    __syncthreads();

    float acc = 0.0f;
    const float* eb = enc_raw + (size_t)b * 256 + tid;
    for (int s = 0; s < len; s++) acc += sc[s] * eb[(size_t)s * (B_ * H_)];
    ctx_out[((size_t)b * T_ + t) * 256 + tid] = acc;
    combined_out[((size_t)t * B_ + b) * 512 + tid] = acc;
}

// ---------------------------------------------------------------------------
// Kernel 4: logits GEMM — 128x128 tiles, 1024 threads. grid 4x8 covers
// M=512, N=1000 (guarded).
// ---------------------------------------------------------------------------
__global__ __launch_bounds__(1024, 4)
void gemm_logits(const float* __restrict__ A, const float* __restrict__ Bw,
                 const float* __restrict__ bias, float* __restrict__ C)
{
    __shared__ float As2[32][132];
    __shared__ float Bs2[32][132];
    gemm_tile_1024(A, nullptr, 512, Bw, bias, C, V_, 512, V_,
                   (int)blockIdx.y * 128, (int)blockIdx.x * 128, As2, Bs2);
}

// ---------------------------------------------------------------------------
// Kernel 5: vocab softmax. Block per (t,b) row, 256 threads x 4 (V=1000).
// ---------------------------------------------------------------------------
__global__ __launch_bounds__(256)
void vocab_softmax(const float* __restrict__ logits, float* __restrict__ probs)
{
    const int r = blockIdx.x;
    const int tid = threadIdx.x;
    const int wv = tid >> 6, lane = tid & 63;
    __shared__ float red[8];
    const float* row = logits + (size_t)r * V_;
    float v[4];
    float mx = -INFINITY;
    #pragma unroll
    for (int j = 0; j < 4; j++) {
        int idx = tid + 256 * j;
        v[j] = (idx < V_) ? row[idx] : -INFINITY;
        mx = fmaxf(mx, v[j]);
    }
    #pragma unroll
    for (int off = 32; off >= 1; off >>= 1) mx = fmaxf(mx, __shfl_xor(mx, off, 64));
    if (lane == 0) red[wv] = mx;
    __syncthreads();
    mx = fmaxf(fmaxf(red[0], red[1]), fmaxf(red[2], red[3]));
    float s = 0.0f;
    #pragma unroll
    for (int j = 0; j < 4; j++) {
        v[j] = __expf(v[j] - mx);
        s += v[j];
    }
    #pragma unroll
    for (int off = 32; off >= 1; off >>= 1) s += __shfl_xor(s, off, 64);
    if (lane == 0) red[4 + wv] = s;
    __syncthreads();
    s = red[4] + red[5] + red[6] + red[7];
    float inv = 1.0f / s;
    #pragma unroll
    for (int j = 0; j < 4; j++) {
        int idx = tid + 256 * j;
        if (idx < V_) probs[(size_t)r * V_ + idx] = v[j] * inv;
    }
}

extern "C" void kernel_launch(void* const* d_in, const int* in_sizes, int n_in,
                              void* d_out, int out_size, void* d_ws, size_t ws_size,
                              hipStream_t stream) {
    const int*   tv       = (const int*)d_in[0];
    const float* h0       = (const float*)d_in[1];
    const float* c0       = (const float*)d_in[2];
    const float* enc_raw  = (const float*)d_in[3];
    const int*   lens     = (const int*)d_in[4];
    const float* emb      = (const float*)d_in[5];
    const float* W_ih     = (const float*)d_in[6];
    const float* W_hh     = (const float*)d_in[7];
    const float* b_ih     = (const float*)d_in[8];
    const float* b_hh     = (const float*)d_in[9];
    const float* We       = (const float*)d_in[10];
    const float* be       = (const float*)d_in[11];
    const float* Wd       = (const float*)d_in[12];
    const float* bd       = (const float*)d_in[13];
    const float* wa       = (const float*)d_in[14];
    const float* ba       = (const float*)d_in[15];
    const float* W_out    = (const float*)d_in[16];
    const float* b_out    = (const float*)d_in[17];

    // workspace layout (fp32 words; proven 14.63 MB footprint)
    float* ws       = (float*)d_ws;
    float* enct     = ws;                       // [8192,256]  2,097,152
    float* xproj    = ws + 2097152;             // [512,1024]    524,288
    float* Wdt      = ws + 2621440;             // [256,256]      65,536
    float* logits   = ws + 2752512;             // [512,1000]    512,000
    float* combined = ws + 3264512;             // [512,512]     262,144
    u16*   Wt       = (u16*)(ws + 3526656);     // [256,1024] bf16

    // d_out layout (fp32): probs [T,B,V], hT, cT, ctx [B,T,H]
    float* out      = (float*)d_out;
    float* probs    = out;
    float* hT       = out + 512000;
    float* cT       = out + 520192;
    float* ctx_out  = out + 528384;

    // 1) xproj GEMM (128x128 tiles) + transposes
    prep_xproj<<<352, 1024, 0, stream>>>(emb, tv, W_ih, b_ih, xproj, W_hh, Wt, Wd, Wdt);
    // 2) LSTM (blocks 0-31, uint2 loads) + enc_t GEMM (blocks 32-159)
    lstm_enct<<<160, 1024, 0, stream>>>(xproj, Wt, b_hh, h0, c0, combined, hT, cT,
                                        enc_raw, We, be, enct);
    // 3) attention with inlined dec_t
    attn2<<<512, 256, 0, stream>>>(enct, combined, Wdt, bd, enc_raw, wa, ba, lens,
                                   ctx_out, combined);
    // 4) logits = combined @ W_out^T + b_out (128x128 tiles)
    {
        dim3 grid(8, 4);
        gemm_logits<<<grid, 1024, 0, stream>>>(combined, W_out, b_out, logits);
    }
    // 5) vocab softmax
    vocab_softmax<<<512, 256, 0, stream>>>(logits, probs);
}

// Round 11
// 298.898 us; speedup vs baseline: 1.3102x; 1.3102x over previous
//
#include <hip/hip_runtime.h>
#include <math.h>

typedef unsigned int u32;
typedef unsigned short u16;

#define T_ 16
#define B_ 32
#define S_ 256
#define H_ 256
#define E_ 300
#define V_ 1000

__device__ __forceinline__ float fast_tanh(float x) {
    return 1.0f - 2.0f / (__expf(2.0f * x) + 1.0f);
}
__device__ __forceinline__ float fast_sigm(float x) {
    return 1.0f / (1.0f + __expf(-x));
}
__device__ __forceinline__ float bf2f(u16 x) { return __uint_as_float(((u32)x) << 16); }
__device__ __forceinline__ float blo(u32 u) { return __uint_as_float(u << 16); }
__device__ __forceinline__ float bhi(u32 u) { return __uint_as_float(u & 0xffff0000u); }
__device__ __forceinline__ u16 f2bf(float f) {
    u32 u = __float_as_uint(f);
    u32 r = (u + 0x7fffu + ((u >> 16) & 1u)) >> 16;
    return (u16)r;
}

// ---------------------------------------------------------------------------
// GEMM tile device fn: 64x64 tile, BK=32, 256 threads, 4x4/thread.
// (Round-9 proven: at M<=512, many small blocks across CUs beat 128x128
// tiles on few CUs — round-10 lesson.)
// ---------------------------------------------------------------------------
__device__ void gemm_tile_256(const float* __restrict__ A, const int* __restrict__ gidx,
                              int lda, const float* __restrict__ Bw,
                              const float* __restrict__ bias, float* __restrict__ C,
                              int N, int K, int ldc, int bm, int bn)
{
    __shared__ float As[32][64];
    __shared__ float Bs[32][64];
    const int tid = threadIdx.x;
    const int ty = tid >> 4, tx = tid & 15;
    const int lr = tid >> 2;
    const int lk = (tid & 3) * 8;

    int am = bm + lr;
    int arow = gidx ? gidx[am] : am;
    const float* Ap = A + (size_t)arow * lda;
    int bnr = bn + lr;
    const float* Bp = (bnr < N) ? (Bw + (size_t)bnr * K) : nullptr;

    float acc[4][4] = {};

    for (int k0 = 0; k0 < K; k0 += 32) {
        int kb = k0 + lk;
        float av[8];
        if (kb + 8 <= K) {
            float4 p0 = *(const float4*)(Ap + kb);
            float4 p1 = *(const float4*)(Ap + kb + 4);
            av[0]=p0.x; av[1]=p0.y; av[2]=p0.z; av[3]=p0.w;
            av[4]=p1.x; av[5]=p1.y; av[6]=p1.z; av[7]=p1.w;
        } else {
            #pragma unroll
            for (int j = 0; j < 8; j++) av[j] = (kb + j < K) ? Ap[kb + j] : 0.0f;
        }
        #pragma unroll
        for (int j = 0; j < 8; j++) As[lk + j][lr] = av[j];
        if (Bp && kb + 8 <= K) {
            float4 p0 = *(const float4*)(Bp + kb);
            float4 p1 = *(const float4*)(Bp + kb + 4);
            av[0]=p0.x; av[1]=p0.y; av[2]=p0.z; av[3]=p0.w;
            av[4]=p1.x; av[5]=p1.y; av[6]=p1.z; av[7]=p1.w;
        } else if (Bp) {
            #pragma unroll
            for (int j = 0; j < 8; j++) av[j] = (kb + j < K) ? Bp[kb + j] : 0.0f;
        } else {
            #pragma unroll
            for (int j = 0; j < 8; j++) av[j] = 0.0f;
        }
        #pragma unroll
        for (int j = 0; j < 8; j++) Bs[lk + j][lr] = av[j];
        __syncthreads();
        #pragma unroll
        for (int kk = 0; kk < 32; kk++) {
            float4 a = *(const float4*)&As[kk][ty * 4];
            float4 b = *(const float4*)&Bs[kk][tx * 4];
            acc[0][0] += a.x*b.x; acc[0][1] += a.x*b.y; acc[0][2] += a.x*b.z; acc[0][3] += a.x*b.w;
            acc[1][0] += a.y*b.x; acc[1][1] += a.y*b.y; acc[1][2] += a.y*b.z; acc[1][3] += a.y*b.w;
            acc[2][0] += a.z*b.x; acc[2][1] += a.z*b.y; acc[2][2] += a.z*b.z; acc[2][3] += a.z*b.w;
            acc[3][0] += a.w*b.x; acc[3][1] += a.w*b.y; acc[3][2] += a.w*b.z; acc[3][3] += a.w*b.w;
        }
        __syncthreads();
    }
    #pragma unroll
    for (int i = 0; i < 4; i++) {
        int m = bm + ty * 4 + i;
        #pragma unroll
        for (int j = 0; j < 4; j++) {
            int n = bn + tx * 4 + j;
            if (n < N) C[(size_t)m * ldc + n] = acc[i][j] + bias[n];
        }
    }
}

// ---------------------------------------------------------------------------
// Kernel 1: prep — xproj GEMM (64x64 tiles) + transposes. 256 thr/block.
//   bid <  128         : xproj tile (M=512, N=1024, K=300, gather emb)
//   128  <= bid < 1152 : Wt[k*1024+r]   = bf16(Whh[r*256+k])
//   1152 <= bid < 1408 : Wdt[k*256+h]   = Wd[h*256+k]
//   1408 <= bid < 1920 : WoT[k*1000+v]  = W_out[v*512+k]   (k = bid-1408)
// ---------------------------------------------------------------------------
__global__ __launch_bounds__(256)
void prep_xproj(const float* __restrict__ emb, const int* __restrict__ tv,
                const float* __restrict__ W_ih, const float* __restrict__ b_ih,
                float* __restrict__ xproj,
                const float* __restrict__ Whh, u16* __restrict__ Wt,
                const float* __restrict__ Wd, float* __restrict__ Wdt,
                const float* __restrict__ W_out, float* __restrict__ WoT)
{
    const int bid = blockIdx.x;
    if (bid < 128) {
        gemm_tile_256(emb, tv, E_, W_ih, b_ih, xproj, 1024, E_, 1024,
                      (bid >> 4) * 64, (bid & 15) * 64);
    } else if (bid < 1152) {
        int idx = (bid - 128) * 256 + threadIdx.x;   // 0..262143
        int k = idx >> 10;
        int r = idx & 1023;
        Wt[idx] = f2bf(Whh[(size_t)r * 256 + k]);
    } else if (bid < 1408) {
        int idx = (bid - 1152) * 256 + threadIdx.x;  // 0..65535
        int k = idx >> 8;
        int h = idx & 255;
        Wdt[idx] = Wd[(size_t)h * 256 + k];
    } else {
        int k = bid - 1408;                          // 0..511
        #pragma unroll
        for (int j = 0; j < 4; j++) {
            int v = threadIdx.x + 256 * j;
            if (v < V_) WoT[(size_t)k * V_ + v] = W_out[(size_t)v * 512 + k];
        }
    }
}

// ---------------------------------------------------------------------------
// Kernel 2: heterogeneous lstm + enc_t (exact round-9 code, 316-us config).
//   bid < 32 : LSTM scan — u32 W loads, 2-way k-split, unroll-2 cap (VGPR ~32,
//              no spill). bid >= 32: enc_t 128x128 tile on idle CUs.
// ---------------------------------------------------------------------------
__global__ __launch_bounds__(1024, 4)
void lstm_enct(const float* __restrict__ xproj,   // [T,B,1024]
               const u16*   __restrict__ Wt,      // [256,1024] bf16
               const float* __restrict__ bhh,     // [1024]
               const float* __restrict__ h0, const float* __restrict__ c0,
               float* __restrict__ combined,      // [T,B,512] second half
               float* __restrict__ hT, float* __restrict__ cT,
               const float* __restrict__ enc_raw, // [8192,256]
               const float* __restrict__ We,      // [256,256]
               const float* __restrict__ be,
               float* __restrict__ enct)          // [8192,256]
{
    const int bid = blockIdx.x;
    const int tid = threadIdx.x;
    __shared__ float hs[256], cs[256];
    __shared__ float zp[2][1024];
    __shared__ float As2[32][132];
    __shared__ float Bs2[32][132];

    if (bid < 32) {
        const int b  = bid;
        const int kg = tid >> 9;          // 0..1
        const int rq = tid & 511;
        const int r0 = rq * 2;
        if (tid < 256) {
            hs[tid] = h0[b * 256 + tid];
            cs[tid] = c0[b * 256 + tid];
        }
        const float bh = bhh[tid];
        const u16* wbase = Wt + (size_t)(kg * 128) * 1024 + r0;
        __syncthreads();

        for (int t = 0; t < T_; t++) {
            float a0 = 0.f, a1 = 0.f;
            #pragma unroll 2
            for (int kk = 0; kk < 128; kk += 4) {
                float4 h4 = *(const float4*)&hs[kg * 128 + kk];
                u32 w0 = *(const u32*)(wbase + (size_t)(kk + 0) * 1024);
                u32 w1 = *(const u32*)(wbase + (size_t)(kk + 1) * 1024);
                u32 w2 = *(const u32*)(wbase + (size_t)(kk + 2) * 1024);
                u32 w3 = *(const u32*)(wbase + (size_t)(kk + 3) * 1024);
                a0 += blo(w0)*h4.x; a1 += bhi(w0)*h4.x;
                a0 += blo(w1)*h4.y; a1 += bhi(w1)*h4.y;
                a0 += blo(w2)*h4.z; a1 += bhi(w2)*h4.z;
                a0 += blo(w3)*h4.w; a1 += bhi(w3)*h4.w;
            }
            *(float2*)&zp[kg][r0] = make_float2(a0, a1);
            __syncthreads();

            float z = xproj[((size_t)t * B_ + b) * 1024 + tid] + bh
                    + zp[0][tid] + zp[1][tid];
            __syncthreads();
            zp[0][tid] = z;
            __syncthreads();

            if (tid < 256) {
                float ig = fast_sigm(zp[0][tid]);
                float fg = fast_sigm(zp[0][256 + tid]);
                float gg = fast_tanh(zp[0][512 + tid]);
                float og = fast_sigm(zp[0][768 + tid]);
                float c = fg * cs[tid] + ig * gg;
                float h = og * fast_tanh(c);
                cs[tid] = c;
                hs[tid] = h;
                combined[((size_t)t * B_ + b) * 512 + 256 + tid] = h;
                if (t == T_ - 1) {
                    hT[b * 256 + tid] = h;
                    cT[b * 256 + tid] = c;
                }
            }
            __syncthreads();
        }
    } else {
        // enc_t 128x128 tile (inline round-9 code)
        const int tile = bid - 32;
        const int bm = (tile >> 1) * 128;
        const int bn = (tile & 1) * 128;
        const int tx = tid & 31, ty = tid >> 5;
        const int lr = tid >> 3;
        const int lk = (tid & 7) * 4;

        const float* Ap = enc_raw + (size_t)(bm + lr) * 256;
        const float* Bp = We + (size_t)(bn + lr) * 256;
        float acc[4][4] = {};

        for (int k0 = 0; k0 < 256; k0 += 32) {
            float4 a4 = *(const float4*)(Ap + k0 + lk);
            float4 b4 = *(const float4*)(Bp + k0 + lk);
            As2[lk + 0][lr] = a4.x; As2[lk + 1][lr] = a4.y;
            As2[lk + 2][lr] = a4.z; As2[lk + 3][lr] = a4.w;
            Bs2[lk + 0][lr] = b4.x; Bs2[lk + 1][lr] = b4.y;
            Bs2[lk + 2][lr] = b4.z; Bs2[lk + 3][lr] = b4.w;
            __syncthreads();
            #pragma unroll
            for (int kk = 0; kk < 32; kk++) {
                float4 a = *(const float4*)&As2[kk][ty * 4];
                float4 b = *(const float4*)&Bs2[kk][tx * 4];
                acc[0][0] += a.x*b.x; acc[0][1] += a.x*b.y; acc[0][2] += a.x*b.z; acc[0][3] += a.x*b.w;
                acc[1][0] += a.y*b.x; acc[1][1] += a.y*b.y; acc[1][2] += a.y*b.z; acc[1][3] += a.y*b.w;
                acc[2][0] += a.z*b.x; acc[2][1] += a.z*b.y; acc[2][2] += a.z*b.z; acc[2][3] += a.z*b.w;
                acc[3][0] += a.w*b.x; acc[3][1] += a.w*b.y; acc[3][2] += a.w*b.z; acc[3][3] += a.w*b.w;
            }
            __syncthreads();
        }
        #pragma unroll
        for (int i = 0; i < 4; i++) {
            int m = bm + ty * 4 + i;
            #pragma unroll
            for (int j = 0; j < 4; j++) {
                int n = bn + tx * 4 + j;
                enct[(size_t)m * 256 + n] = acc[i][j] + be[n];
            }
        }
    }
}

// ---------------------------------------------------------------------------
// Kernel 3: FUSED tail — dec_t + scores + softmax + context + logits row +
// vocab softmax, one block per (b,t), 256 threads. Logits stay in LDS (no
// HBM round-trip); W_outT read with coalesced float4 (combined[k] broadcast).
// ---------------------------------------------------------------------------
__global__ __launch_bounds__(256)
void attn_logits(const float* __restrict__ enct,        // [S,B,H]
                 const float* __restrict__ combined_in, // [T,B,512] (2nd half)
                 const float* __restrict__ Wdt,         // [256,256] k-major
                 const float* __restrict__ bd,
                 const float* __restrict__ enc_raw,     // [S,B,H]
                 const float* __restrict__ wa, const float* __restrict__ ba,
                 const int* __restrict__ lens,
                 const float* __restrict__ WoT,         // [512,1000] k-major
                 const float* __restrict__ b_out,       // [1000]
                 float* __restrict__ ctx_out,           // [B,T,H] (d_out)
                 float* __restrict__ probs)             // [T,B,V] (d_out)
{
    const int bid = blockIdx.x;
    const int b = bid >> 4;
    const int t = bid & 15;
    const int tid = threadIdx.x;
    __shared__ float ds[256], was[256], sc[256];
    __shared__ float crow[512];     // [context | out]
    __shared__ float lrow[1000];
    __shared__ float red[8];

    float outv = combined_in[((size_t)t * B_ + b) * 512 + 256 + tid];
    crow[256 + tid] = outv;
    was[tid] = wa[tid];
    const int len = lens[b];
    const float bav = ba[0];
    __syncthreads();

    // dec_t row (coalesced via Wdt)
    {
        float acc = bd[tid];
        const float* wp = Wdt + tid;
        #pragma unroll 4
        for (int k = 0; k < 256; k++) acc += wp[(size_t)k * 256] * crow[256 + k];
        ds[tid] = acc;
    }
    __syncthreads();

    const int wv = tid >> 6, lane = tid & 63;
    for (int s = wv; s < len; s += 4) {
        const float* er = enct + ((size_t)s * B_ + b) * 256;
        float sum = 0.0f;
        #pragma unroll
        for (int j = 0; j < 4; j++) {
            int h = lane + 64 * j;
            sum += fast_tanh(er[h] + ds[h]) * was[h];
        }
        #pragma unroll
        for (int off = 32; off >= 1; off >>= 1) sum += __shfl_xor(sum, off, 64);
        if (lane == 0) sc[s] = sum + bav;
    }
    __syncthreads();

    // masked softmax over s
    float x = (tid < len) ? sc[tid] : -INFINITY;
    float m = x;
    #pragma unroll
    for (int off = 32; off >= 1; off >>= 1) m = fmaxf(m, __shfl_xor(m, off, 64));
    if (lane == 0) red[wv] = m;
    __syncthreads();
    m = fmaxf(fmaxf(red[0], red[1]), fmaxf(red[2], red[3]));
    float e = __expf(x - m);
    float ssum = e;
    #pragma unroll
    for (int off = 32; off >= 1; off >>= 1) ssum += __shfl_xor(ssum, off, 64);
    if (lane == 0) red[4 + wv] = ssum;
    __syncthreads();
    ssum = red[4] + red[5] + red[6] + red[7];
    __syncthreads();
    sc[tid] = e / ssum;
    __syncthreads();

    // context
    float cacc = 0.0f;
    const float* eb = enc_raw + (size_t)b * 256 + tid;
    for (int s = 0; s < len; s++) cacc += sc[s] * eb[(size_t)s * (B_ * H_)];
    ctx_out[((size_t)b * T_ + t) * 256 + tid] = cacc;
    crow[tid] = cacc;
    __syncthreads();

    // logits row: v0 = tid*4, K=512, coalesced float4 from WoT
    if (tid < 250) {
        const int v0 = tid * 4;
        float4 a = *(const float4*)(b_out + v0);
        const float* wp = WoT + v0;
        #pragma unroll 4
        for (int k = 0; k < 512; k++) {
            float c = crow[k];
            float4 w = *(const float4*)(wp + (size_t)k * V_);
            a.x += c * w.x; a.y += c * w.y; a.z += c * w.z; a.w += c * w.w;
        }
        *(float4*)&lrow[v0] = a;
    }
    __syncthreads();

    // vocab softmax from LDS
    float v[4];
    float mx = -INFINITY;
    #pragma unroll
    for (int j = 0; j < 4; j++) {
        int idx = tid + 256 * j;
        v[j] = (idx < V_) ? lrow[idx] : -INFINITY;
        mx = fmaxf(mx, v[j]);
    }
    #pragma unroll
    for (int off = 32; off >= 1; off >>= 1) mx = fmaxf(mx, __shfl_xor(mx, off, 64));
    if (lane == 0) red[wv] = mx;
    __syncthreads();
    mx = fmaxf(fmaxf(red[0], red[1]), fmaxf(red[2], red[3]));
    float s2 = 0.0f;
    #pragma unroll
    for (int j = 0; j < 4; j++) {
        v[j] = __expf(v[j] - mx);
        s2 += v[j];
    }
    #pragma unroll
    for (int off = 32; off >= 1; off >>= 1) s2 += __shfl_xor(s2, off, 64);
    if (lane == 0) red[4 + wv] = s2;
    __syncthreads();
    s2 = red[4] + red[5] + red[6] + red[7];
    float inv = 1.0f / s2;
    #pragma unroll
    for (int j = 0; j < 4; j++) {
        int idx = tid + 256 * j;
        if (idx < V_) probs[((size_t)t * B_ + b) * V_ + idx] = v[j] * inv;
    }
}

extern "C" void kernel_launch(void* const* d_in, const int* in_sizes, int n_in,
                              void* d_out, int out_size, void* d_ws, size_t ws_size,
                              hipStream_t stream) {
    const int*   tv       = (const int*)d_in[0];
    const float* h0       = (const float*)d_in[1];
    const float* c0       = (const float*)d_in[2];
    const float* enc_raw  = (const float*)d_in[3];
    const int*   lens     = (const int*)d_in[4];
    const float* emb      = (const float*)d_in[5];
    const float* W_ih     = (const float*)d_in[6];
    const float* W_hh     = (const float*)d_in[7];
    const float* b_ih     = (const float*)d_in[8];
    const float* b_hh     = (const float*)d_in[9];
    const float* We       = (const float*)d_in[10];
    const float* be       = (const float*)d_in[11];
    const float* Wd       = (const float*)d_in[12];
    const float* bd       = (const float*)d_in[13];
    const float* wa       = (const float*)d_in[14];
    const float* ba       = (const float*)d_in[15];
    const float* W_out    = (const float*)d_in[16];
    const float* b_out    = (const float*)d_in[17];

    // workspace layout (fp32 words; proven 14.63 MB footprint; logits slot
    // now holds W_outT — exact same 512,000-word size)
    float* ws       = (float*)d_ws;
    float* enct     = ws;                       // [8192,256]  2,097,152
    float* xproj    = ws + 2097152;             // [512,1024]    524,288
    float* Wdt      = ws + 2621440;             // [256,256]      65,536
    float* WoT      = ws + 2752512;             // [512,1000]    512,000
    float* combined = ws + 3264512;             // [512,512]     262,144
    u16*   Wt       = (u16*)(ws + 3526656);     // [256,1024] bf16

    // d_out layout (fp32): probs [T,B,V], hT, cT, ctx [B,T,H]
    float* out      = (float*)d_out;
    float* probs    = out;
    float* hT       = out + 512000;
    float* cT       = out + 520192;
    float* ctx_out  = out + 528384;

    // 1) xproj GEMM + Whh/Wd/W_out transposes
    prep_xproj<<<1920, 256, 0, stream>>>(emb, tv, W_ih, b_ih, xproj,
                                         W_hh, Wt, Wd, Wdt, W_out, WoT);
    // 2) LSTM (blocks 0-31) + enc_t GEMM (blocks 32-159)
    lstm_enct<<<160, 1024, 0, stream>>>(xproj, Wt, b_hh, h0, c0, combined, hT, cT,
                                        enc_raw, We, be, enct);
    // 3) fused attention + logits + vocab softmax
    attn_logits<<<512, 256, 0, stream>>>(enct, combined, Wdt, bd, enc_raw,
                                         wa, ba, lens, WoT, b_out, ctx_out, probs);
}

// Round 12
// 287.873 us; speedup vs baseline: 1.3603x; 1.0383x over previous
//
#include <hip/hip_runtime.h>
#include <math.h>

typedef unsigned int u32;
typedef unsigned short u16;

#define T_ 16
#define B_ 32
#define S_ 256
#define H_ 256
#define E_ 300
#define V_ 1000

__device__ __forceinline__ float fast_tanh(float x) {
    return 1.0f - 2.0f / (__expf(2.0f * x) + 1.0f);
}
__device__ __forceinline__ float fast_sigm(float x) {
    return 1.0f / (1.0f + __expf(-x));
}
__device__ __forceinline__ float bf2f(u16 x) { return __uint_as_float(((u32)x) << 16); }
__device__ __forceinline__ float blo(u32 u) { return __uint_as_float(u << 16); }
__device__ __forceinline__ float bhi(u32 u) { return __uint_as_float(u & 0xffff0000u); }
__device__ __forceinline__ u16 f2bf(float f) {
    u32 u = __float_as_uint(f);
    u32 r = (u + 0x7fffu + ((u >> 16) & 1u)) >> 16;
    return (u16)r;
}

// ---------------------------------------------------------------------------
// GEMM tile: 64x64, BK=32, 256 threads, 4x4/thread (round-9 proven; at M<=512
// many small blocks across CUs beat 128x128 tiles on few CUs — round-10).
// ---------------------------------------------------------------------------
__device__ void gemm_tile_256(const float* __restrict__ A, const int* __restrict__ gidx,
                              int lda, const float* __restrict__ Bw,
                              const float* __restrict__ bias, float* __restrict__ C,
                              int N, int K, int ldc, int bm, int bn)
{
    __shared__ float As[32][64];
    __shared__ float Bs[32][64];
    const int tid = threadIdx.x;
    const int ty = tid >> 4, tx = tid & 15;
    const int lr = tid >> 2;
    const int lk = (tid & 3) * 8;

    int am = bm + lr;
    int arow = gidx ? gidx[am] : am;
    const float* Ap = A + (size_t)arow * lda;
    int bnr = bn + lr;
    const float* Bp = (bnr < N) ? (Bw + (size_t)bnr * K) : nullptr;

    float acc[4][4] = {};

    for (int k0 = 0; k0 < K; k0 += 32) {
        int kb = k0 + lk;
        float av[8];
        if (kb + 8 <= K) {
            float4 p0 = *(const float4*)(Ap + kb);
            float4 p1 = *(const float4*)(Ap + kb + 4);
            av[0]=p0.x; av[1]=p0.y; av[2]=p0.z; av[3]=p0.w;
            av[4]=p1.x; av[5]=p1.y; av[6]=p1.z; av[7]=p1.w;
        } else {
            #pragma unroll
            for (int j = 0; j < 8; j++) av[j] = (kb + j < K) ? Ap[kb + j] : 0.0f;
        }
        #pragma unroll
        for (int j = 0; j < 8; j++) As[lk + j][lr] = av[j];
        if (Bp && kb + 8 <= K) {
            float4 p0 = *(const float4*)(Bp + kb);
            float4 p1 = *(const float4*)(Bp + kb + 4);
            av[0]=p0.x; av[1]=p0.y; av[2]=p0.z; av[3]=p0.w;
            av[4]=p1.x; av[5]=p1.y; av[6]=p1.z; av[7]=p1.w;
        } else if (Bp) {
            #pragma unroll
            for (int j = 0; j < 8; j++) av[j] = (kb + j < K) ? Bp[kb + j] : 0.0f;
        } else {
            #pragma unroll
            for (int j = 0; j < 8; j++) av[j] = 0.0f;
        }
        #pragma unroll
        for (int j = 0; j < 8; j++) Bs[lk + j][lr] = av[j];
        __syncthreads();
        #pragma unroll
        for (int kk = 0; kk < 32; kk++) {
            float4 a = *(const float4*)&As[kk][ty * 4];
            float4 b = *(const float4*)&Bs[kk][tx * 4];
            acc[0][0] += a.x*b.x; acc[0][1] += a.x*b.y; acc[0][2] += a.x*b.z; acc[0][3] += a.x*b.w;
            acc[1][0] += a.y*b.x; acc[1][1] += a.y*b.y; acc[1][2] += a.y*b.z; acc[1][3] += a.y*b.w;
            acc[2][0] += a.z*b.x; acc[2][1] += a.z*b.y; acc[2][2] += a.z*b.z; acc[2][3] += a.z*b.w;
            acc[3][0] += a.w*b.x; acc[3][1] += a.w*b.y; acc[3][2] += a.w*b.z; acc[3][3] += a.w*b.w;
        }
        __syncthreads();
    }
    #pragma unroll
    for (int i = 0; i < 4; i++) {
        int m = bm + ty * 4 + i;
        #pragma unroll
        for (int j = 0; j < 4; j++) {
            int n = bn + tx * 4 + j;
            if (n < N) C[(size_t)m * ldc + n] = acc[i][j] + bias[n];
        }
    }
}

// ---------------------------------------------------------------------------
// Kernel 1: prep — xproj GEMM (64x64 tiles) + transposes. 256 thr/block.
//   bid <  128         : xproj tile (M=512, N=1024, K=300, gather emb)
//   128  <= bid < 1152 : Wt[k*1024+r]  = bf16(Whh[r*256+k])
//   1152 <= bid < 1408 : Wdt[k*256+h]  = Wd[h*256+k]
//   1408 <= bid < 1920 : WoTb[k*1000+v]= bf16(W_out[v*512+k])  (k = bid-1408)
// ---------------------------------------------------------------------------
__global__ __launch_bounds__(256)
void prep_xproj(const float* __restrict__ emb, const int* __restrict__ tv,
                const float* __restrict__ W_ih, const float* __restrict__ b_ih,
                float* __restrict__ xproj,
                const float* __restrict__ Whh, u16* __restrict__ Wt,
                const float* __restrict__ Wd, float* __restrict__ Wdt,
                const float* __restrict__ W_out, u16* __restrict__ WoTb)
{
    const int bid = blockIdx.x;
    if (bid < 128) {
        gemm_tile_256(emb, tv, E_, W_ih, b_ih, xproj, 1024, E_, 1024,
                      (bid >> 4) * 64, (bid & 15) * 64);
    } else if (bid < 1152) {
        int idx = (bid - 128) * 256 + threadIdx.x;   // 0..262143
        int k = idx >> 10;
        int r = idx & 1023;
        Wt[idx] = f2bf(Whh[(size_t)r * 256 + k]);
    } else if (bid < 1408) {
        int idx = (bid - 1152) * 256 + threadIdx.x;  // 0..65535
        int k = idx >> 8;
        int h = idx & 255;
        Wdt[idx] = Wd[(size_t)h * 256 + k];
    } else {
        int k = bid - 1408;                          // 0..511
        #pragma unroll
        for (int j = 0; j < 4; j++) {
            int v = threadIdx.x + 256 * j;
            if (v < V_) WoTb[(size_t)k * V_ + v] = f2bf(W_out[(size_t)v * 512 + k]);
        }
    }
}

// ---------------------------------------------------------------------------
// Kernel 2: heterogeneous lstm + enc_t (round-9 proven, 316-us config).
// ---------------------------------------------------------------------------
__global__ __launch_bounds__(1024, 4)
void lstm_enct(const float* __restrict__ xproj,   // [T,B,1024]
               const u16*   __restrict__ Wt,      // [256,1024] bf16
               const float* __restrict__ bhh,     // [1024]
               const float* __restrict__ h0, const float* __restrict__ c0,
               float* __restrict__ combined,      // [T,B,512] second half
               float* __restrict__ hT, float* __restrict__ cT,
               const float* __restrict__ enc_raw, // [8192,256]
               const float* __restrict__ We,      // [256,256]
               const float* __restrict__ be,
               float* __restrict__ enct)          // [8192,256]
{
    const int bid = blockIdx.x;
    const int tid = threadIdx.x;
    __shared__ float hs[256], cs[256];
    __shared__ float zp[2][1024];
    __shared__ float As2[32][132];
    __shared__ float Bs2[32][132];

    if (bid < 32) {
        const int b  = bid;
        const int kg = tid >> 9;          // 0..1
        const int rq = tid & 511;
        const int r0 = rq * 2;
        if (tid < 256) {
            hs[tid] = h0[b * 256 + tid];
            cs[tid] = c0[b * 256 + tid];
        }
        const float bh = bhh[tid];
        const u16* wbase = Wt + (size_t)(kg * 128) * 1024 + r0;
        __syncthreads();

        for (int t = 0; t < T_; t++) {
            float a0 = 0.f, a1 = 0.f;
            #pragma unroll 2
            for (int kk = 0; kk < 128; kk += 4) {
                float4 h4 = *(const float4*)&hs[kg * 128 + kk];
                u32 w0 = *(const u32*)(wbase + (size_t)(kk + 0) * 1024);
                u32 w1 = *(const u32*)(wbase + (size_t)(kk + 1) * 1024);
                u32 w2 = *(const u32*)(wbase + (size_t)(kk + 2) * 1024);
                u32 w3 = *(const u32*)(wbase + (size_t)(kk + 3) * 1024);
                a0 += blo(w0)*h4.x; a1 += bhi(w0)*h4.x;
                a0 += blo(w1)*h4.y; a1 += bhi(w1)*h4.y;
                a0 += blo(w2)*h4.z; a1 += bhi(w2)*h4.z;
                a0 += blo(w3)*h4.w; a1 += bhi(w3)*h4.w;
            }
            *(float2*)&zp[kg][r0] = make_float2(a0, a1);
            __syncthreads();

            float z = xproj[((size_t)t * B_ + b) * 1024 + tid] + bh
                    + zp[0][tid] + zp[1][tid];
            __syncthreads();
            zp[0][tid] = z;
            __syncthreads();

            if (tid < 256) {
                float ig = fast_sigm(zp[0][tid]);
                float fg = fast_sigm(zp[0][256 + tid]);
                float gg = fast_tanh(zp[0][512 + tid]);
                float og = fast_sigm(zp[0][768 + tid]);
                float c = fg * cs[tid] + ig * gg;
                float h = og * fast_tanh(c);
                cs[tid] = c;
                hs[tid] = h;
                combined[((size_t)t * B_ + b) * 512 + 256 + tid] = h;
                if (t == T_ - 1) {
                    hT[b * 256 + tid] = h;
                    cT[b * 256 + tid] = c;
                }
            }
            __syncthreads();
        }
    } else {
        const int tile = bid - 32;
        const int bm = (tile >> 1) * 128;
        const int bn = (tile & 1) * 128;
        const int tx = tid & 31, ty = tid >> 5;
        const int lr = tid >> 3;
        const int lk = (tid & 7) * 4;

        const float* Ap = enc_raw + (size_t)(bm + lr) * 256;
        const float* Bp = We + (size_t)(bn + lr) * 256;
        float acc[4][4] = {};

        for (int k0 = 0; k0 < 256; k0 += 32) {
            float4 a4 = *(const float4*)(Ap + k0 + lk);
            float4 b4 = *(const float4*)(Bp + k0 + lk);
            As2[lk + 0][lr] = a4.x; As2[lk + 1][lr] = a4.y;
            As2[lk + 2][lr] = a4.z; As2[lk + 3][lr] = a4.w;
            Bs2[lk + 0][lr] = b4.x; Bs2[lk + 1][lr] = b4.y;
            Bs2[lk + 2][lr] = b4.z; Bs2[lk + 3][lr] = b4.w;
            __syncthreads();
            #pragma unroll
            for (int kk = 0; kk < 32; kk++) {
                float4 a = *(const float4*)&As2[kk][ty * 4];
                float4 b = *(const float4*)&Bs2[kk][tx * 4];
                acc[0][0] += a.x*b.x; acc[0][1] += a.x*b.y; acc[0][2] += a.x*b.z; acc[0][3] += a.x*b.w;
                acc[1][0] += a.y*b.x; acc[1][1] += a.y*b.y; acc[1][2] += a.y*b.z; acc[1][3] += a.y*b.w;
                acc[2][0] += a.z*b.x; acc[2][1] += a.z*b.y; acc[2][2] += a.z*b.z; acc[2][3] += a.z*b.w;
                acc[3][0] += a.w*b.x; acc[3][1] += a.w*b.y; acc[3][2] += a.w*b.z; acc[3][3] += a.w*b.w;
            }
            __syncthreads();
        }
        #pragma unroll
        for (int i = 0; i < 4; i++) {
            int m = bm + ty * 4 + i;
            #pragma unroll
            for (int j = 0; j < 4; j++) {
                int n = bn + tx * 4 + j;
                enct[(size_t)m * 256 + n] = acc[i][j] + be[n];
            }
        }
    }
}

// ---------------------------------------------------------------------------
// Kernel 3: FUSED tail v2 — 512 threads/block (16 waves/CU = 2x round-11
// occupancy; every latency chain split in half across thread groups).
// Block (b,t) with b = bid&31 (XCD swizzle: all 16 t-blocks of a batch land
// on one XCD -> enct/enc_raw slices fetched once per XCD, not 8x).
// ---------------------------------------------------------------------------
__global__ __launch_bounds__(512)
void attn_logits(const float* __restrict__ enct,        // [S,B,H]
                 const float* __restrict__ combined_in, // [T,B,512] (2nd half)
                 const float* __restrict__ Wdt,         // [256,256] k-major
                 const float* __restrict__ bd,
                 const float* __restrict__ enc_raw,     // [S,B,H]
                 const float* __restrict__ wa, const float* __restrict__ ba,
                 const int* __restrict__ lens,
                 const u16* __restrict__ WoTb,          // [512,1000] bf16 k-major
                 const float* __restrict__ b_out,       // [1000]
                 float* __restrict__ ctx_out,           // [B,T,H] (d_out)
                 float* __restrict__ probs)             // [T,B,V] (d_out)
{
    const int bid = blockIdx.x;
    const int b = bid & 31;          // XCD swizzle: bid mod 8 == b mod 8
    const int t = bid >> 5;
    const int tid = threadIdx.x;
    const int wv = tid >> 6, lane = tid & 63;   // 8 waves
    __shared__ float ds[256], was[256], sc[256];
    __shared__ float crow[512];      // [context | out]
    __shared__ float tmp2[512];      // dect partials, then ctx partials
    __shared__ float lrow[1000];
    __shared__ float red[8], red2[8];

    if (tid < 256) {
        crow[256 + tid] = combined_in[((size_t)t * B_ + b) * 512 + 256 + tid];
        was[tid] = wa[tid];
    }
    const int len = lens[b];
    const float bav = ba[0];
    __syncthreads();

    // dec_t row: k-sum split in half across the two 256-thread groups
    {
        const int h  = tid & 255;
        const int k0 = (tid >> 8) * 128;
        float acc = 0.0f;
        const float* wp = Wdt + h;
        #pragma unroll 4
        for (int k = k0; k < k0 + 128; k++) acc += wp[(size_t)k * 256] * crow[256 + k];
        tmp2[tid] = acc;
    }
    __syncthreads();
    if (tid < 256) ds[tid] = bd[tid] + tmp2[tid] + tmp2[tid + 256];
    __syncthreads();

    // scores: 8 waves stride s
    for (int s = wv; s < len; s += 8) {
        const float* er = enct + ((size_t)s * B_ + b) * 256;
        float sum = 0.0f;
        #pragma unroll
        for (int j = 0; j < 4; j++) {
            int h = lane + 64 * j;
            sum += fast_tanh(er[h] + ds[h]) * was[h];
        }
        #pragma unroll
        for (int off = 32; off >= 1; off >>= 1) sum += __shfl_xor(sum, off, 64);
        if (lane == 0) sc[s] = sum + bav;
    }
    __syncthreads();

    // masked softmax over s (8-wave reduction)
    float x = (tid < len) ? sc[tid] : -INFINITY;
    float m = x;
    #pragma unroll
    for (int off = 32; off >= 1; off >>= 1) m = fmaxf(m, __shfl_xor(m, off, 64));
    if (lane == 0) red[wv] = m;
    __syncthreads();
    m = red[0];
    #pragma unroll
    for (int i = 1; i < 8; i++) m = fmaxf(m, red[i]);
    float e = __expf(x - m);
    float ssum = e;
    #pragma unroll
    for (int off = 32; off >= 1; off >>= 1) ssum += __shfl_xor(ssum, off, 64);
    if (lane == 0) red2[wv] = ssum;
    __syncthreads();
    ssum = red2[0] + red2[1] + red2[2] + red2[3] + red2[4] + red2[5] + red2[6] + red2[7];
    if (tid < 256) sc[tid] = e / ssum;
    __syncthreads();

    // context: s-range split in half across the two 256-thread groups
    {
        const int h  = tid & 255;
        const int sg = tid >> 8;
        const int mid = (len + 1) >> 1;
        const int s0 = sg ? mid : 0;
        const int s1 = sg ? len : mid;
        float cacc = 0.0f;
        const float* eb = enc_raw + (size_t)b * 256 + h;
        for (int s = s0; s < s1; s++) cacc += sc[s] * eb[(size_t)s * (B_ * H_)];
        tmp2[tid] = cacc;
    }
    __syncthreads();
    if (tid < 256) {
        float ctx = tmp2[tid] + tmp2[tid + 256];
        ctx_out[((size_t)b * T_ + t) * 256 + tid] = ctx;
        crow[tid] = ctx;
    }
    __syncthreads();

    // logits row: 2 vocab entries per thread, bf16 coalesced u32 loads
    if (tid < 500) {
        const int v0 = tid * 2;
        float a0 = b_out[v0], a1 = b_out[v0 + 1];
        const u32* wp = (const u32*)WoTb + tid;   // row stride 500 u32
        #pragma unroll 4
        for (int k = 0; k < 512; k++) {
            float c = crow[k];
            u32 w = wp[(size_t)k * 500];
            a0 += c * blo(w);
            a1 += c * bhi(w);
        }
        lrow[v0] = a0;
        lrow[v0 + 1] = a1;
    }
    __syncthreads();

    // vocab softmax (2 elems/thread, 8-wave reduction)
    float v0v = -INFINITY, v1v = -INFINITY;
    if (tid < 500) { v0v = lrow[tid * 2]; v1v = lrow[tid * 2 + 1]; }
    float mx = fmaxf(v0v, v1v);
    #pragma unroll
    for (int off = 32; off >= 1; off >>= 1) mx = fmaxf(mx, __shfl_xor(mx, off, 64));
    if (lane == 0) red[wv] = mx;
    __syncthreads();
    mx = red[0];
    #pragma unroll
    for (int i = 1; i < 8; i++) mx = fmaxf(mx, red[i]);
    float e0 = __expf(v0v - mx), e1 = __expf(v1v - mx);
    float s2 = e0 + e1;
    #pragma unroll
    for (int off = 32; off >= 1; off >>= 1) s2 += __shfl_xor(s2, off, 64);
    if (lane == 0) red2[wv] = s2;
    __syncthreads();
    s2 = red2[0] + red2[1] + red2[2] + red2[3] + red2[4] + red2[5] + red2[6] + red2[7];
    float inv = 1.0f / s2;
    if (tid < 500) {
        float2 pv = make_float2(e0 * inv, e1 * inv);
        *(float2*)&probs[((size_t)t * B_ + b) * V_ + tid * 2] = pv;
    }
}

extern "C" void kernel_launch(void* const* d_in, const int* in_sizes, int n_in,
                              void* d_out, int out_size, void* d_ws, size_t ws_size,
                              hipStream_t stream) {
    const int*   tv       = (const int*)d_in[0];
    const float* h0       = (const float*)d_in[1];
    const float* c0       = (const float*)d_in[2];
    const float* enc_raw  = (const float*)d_in[3];
    const int*   lens     = (const int*)d_in[4];
    const float* emb      = (const float*)d_in[5];
    const float* W_ih     = (const float*)d_in[6];
    const float* W_hh     = (const float*)d_in[7];
    const float* b_ih     = (const float*)d_in[8];
    const float* b_hh     = (const float*)d_in[9];
    const float* We       = (const float*)d_in[10];
    const float* be       = (const float*)d_in[11];
    const float* Wd       = (const float*)d_in[12];
    const float* bd       = (const float*)d_in[13];
    const float* wa       = (const float*)d_in[14];
    const float* ba       = (const float*)d_in[15];
    const float* W_out    = (const float*)d_in[16];
    const float* b_out    = (const float*)d_in[17];

    // workspace layout (fp32 words; proven 14.63 MB footprint; WoTb (bf16)
    // occupies the old logits slot)
    float* ws       = (float*)d_ws;
    float* enct     = ws;                       // [8192,256]  2,097,152
    float* xproj    = ws + 2097152;             // [512,1024]    524,288
    float* Wdt      = ws + 2621440;             // [256,256]      65,536
    u16*   WoTb     = (u16*)(ws + 2752512);     // [512,1000] bf16 = 250,000 words
    float* combined = ws + 3264512;             // [512,512]     262,144
    u16*   Wt       = (u16*)(ws + 3526656);     // [256,1024] bf16

    // d_out layout (fp32): probs [T,B,V], hT, cT, ctx [B,T,H]
    float* out      = (float*)d_out;
    float* probs    = out;
    float* hT       = out + 512000;
    float* cT       = out + 520192;
    float* ctx_out  = out + 528384;

    // 1) xproj GEMM + Whh/Wd/W_out transposes
    prep_xproj<<<1920, 256, 0, stream>>>(emb, tv, W_ih, b_ih, xproj,
                                         W_hh, Wt, Wd, Wdt, W_out, WoTb);
    // 2) LSTM (blocks 0-31) + enc_t GEMM (blocks 32-159)
    lstm_enct<<<160, 1024, 0, stream>>>(xproj, Wt, b_hh, h0, c0, combined, hT, cT,
                                        enc_raw, We, be, enct);
    // 3) fused attention + logits + vocab softmax (512 threads, XCD swizzle)
    attn_logits<<<512, 512, 0, stream>>>(enct, combined, Wdt, bd, enc_raw,
                                         wa, ba, lens, WoTb, b_out, ctx_out, probs);
}

// Round 14
// 282.172 us; speedup vs baseline: 1.3878x; 1.0202x over previous
//
#include <hip/hip_runtime.h>
#include <hip/hip_fp16.h>
#include <math.h>

typedef unsigned int u32;
typedef unsigned short u16;

#define T_ 16
#define B_ 32
#define S_ 256
#define H_ 256
#define E_ 300
#define V_ 1000

typedef _Float16 h2_t __attribute__((ext_vector_type(2)));
typedef __fp16  fp16v2 __attribute__((ext_vector_type(2)));

__device__ __forceinline__ float fast_tanh(float x) {
    return 1.0f - 2.0f / (__expf(2.0f * x) + 1.0f);
}
__device__ __forceinline__ float fast_sigm(float x) {
    return 1.0f / (1.0f + __expf(-x));
}
__device__ __forceinline__ float bf2f(u16 x) { return __uint_as_float(((u32)x) << 16); }
__device__ __forceinline__ float blo(u32 u) { return __uint_as_float(u << 16); }
__device__ __forceinline__ float bhi(u32 u) { return __uint_as_float(u & 0xffff0000u); }
__device__ __forceinline__ u16 f2bf(float f) {
    u32 u = __float_as_uint(f);
    u32 r = (u + 0x7fffu + ((u >> 16) & 1u)) >> 16;
    return (u16)r;
}
__device__ __forceinline__ h2_t u2h2(u32 u) {
    union { u32 a; h2_t b; } c; c.a = u; return c.b;
}
// pack two floats to f16x2 (round-to-zero pk conversion), returned as u32 bits
__device__ __forceinline__ u32 pk2(float a, float b) {
    union { fp16v2 v; u32 u; } c; c.v = __builtin_amdgcn_cvt_pkrtz(a, b); return c.u;
}
__device__ __forceinline__ float dot2f16(u32 w, u32 h, float acc) {
#if __has_builtin(__builtin_amdgcn_fdot2)
    return __builtin_amdgcn_fdot2(u2h2(w), u2h2(h), acc, false);
#else
    h2_t wv = u2h2(w), hv = u2h2(h);
    return acc + (float)wv.x * (float)hv.x + (float)wv.y * (float)hv.y;
#endif
}

// ---------------------------------------------------------------------------
// GEMM tile: 64x64, BK=32, 256 threads, 4x4/thread (round-9 proven).
// ---------------------------------------------------------------------------
__device__ void gemm_tile_256(const float* __restrict__ A, const int* __restrict__ gidx,
                              int lda, const float* __restrict__ Bw,
                              const float* __restrict__ bias, float* __restrict__ C,
                              int N, int K, int ldc, int bm, int bn)
{
    __shared__ float As[32][64];
    __shared__ float Bs[32][64];
    const int tid = threadIdx.x;
    const int ty = tid >> 4, tx = tid & 15;
    const int lr = tid >> 2;
    const int lk = (tid & 3) * 8;

    int am = bm + lr;
    int arow = gidx ? gidx[am] : am;
    const float* Ap = A + (size_t)arow * lda;
    int bnr = bn + lr;
    const float* Bp = (bnr < N) ? (Bw + (size_t)bnr * K) : nullptr;

    float acc[4][4] = {};

    for (int k0 = 0; k0 < K; k0 += 32) {
        int kb = k0 + lk;
        float av[8];
        if (kb + 8 <= K) {
            float4 p0 = *(const float4*)(Ap + kb);
            float4 p1 = *(const float4*)(Ap + kb + 4);
            av[0]=p0.x; av[1]=p0.y; av[2]=p0.z; av[3]=p0.w;
            av[4]=p1.x; av[5]=p1.y; av[6]=p1.z; av[7]=p1.w;
        } else {
            #pragma unroll
            for (int j = 0; j < 8; j++) av[j] = (kb + j < K) ? Ap[kb + j] : 0.0f;
        }
        #pragma unroll
        for (int j = 0; j < 8; j++) As[lk + j][lr] = av[j];
        if (Bp && kb + 8 <= K) {
            float4 p0 = *(const float4*)(Bp + kb);
            float4 p1 = *(const float4*)(Bp + kb + 4);
            av[0]=p0.x; av[1]=p0.y; av[2]=p0.z; av[3]=p0.w;
            av[4]=p1.x; av[5]=p1.y; av[6]=p1.z; av[7]=p1.w;
        } else if (Bp) {
            #pragma unroll
            for (int j = 0; j < 8; j++) av[j] = (kb + j < K) ? Bp[kb + j] : 0.0f;
        } else {
            #pragma unroll
            for (int j = 0; j < 8; j++) av[j] = 0.0f;
        }
        #pragma unroll
        for (int j = 0; j < 8; j++) Bs[lk + j][lr] = av[j];
        __syncthreads();
        #pragma unroll
        for (int kk = 0; kk < 32; kk++) {
            float4 a = *(const float4*)&As[kk][ty * 4];
            float4 b = *(const float4*)&Bs[kk][tx * 4];
            acc[0][0] += a.x*b.x; acc[0][1] += a.x*b.y; acc[0][2] += a.x*b.z; acc[0][3] += a.x*b.w;
            acc[1][0] += a.y*b.x; acc[1][1] += a.y*b.y; acc[1][2] += a.y*b.z; acc[1][3] += a.y*b.w;
            acc[2][0] += a.z*b.x; acc[2][1] += a.z*b.y; acc[2][2] += a.z*b.z; acc[2][3] += a.z*b.w;
            acc[3][0] += a.w*b.x; acc[3][1] += a.w*b.y; acc[3][2] += a.w*b.z; acc[3][3] += a.w*b.w;
        }
        __syncthreads();
    }
    #pragma unroll
    for (int i = 0; i < 4; i++) {
        int m = bm + ty * 4 + i;
        #pragma unroll
        for (int j = 0; j < 4; j++) {
            int n = bn + tx * 4 + j;
            if (n < N) C[(size_t)m * ldc + n] = acc[i][j] + bias[n];
        }
    }
}

// ---------------------------------------------------------------------------
// Kernel 1: prep — xproj GEMM (64x64 tiles) + transposes. 256 thr/block.
//   bid <  128        : xproj tile (M=512, N=1024, K=300, gather emb)
//   128  <= bid < 640 : Wt2[kk*1024+r] = pack_f16(Whh[r][2kk], Whh[r][2kk+1])
//   640  <= bid < 896 : Wdt[k*256+h]   = Wd[h*256+k]
//   896  <= bid < 1408: WoTb[k*1000+v] = bf16(W_out[v*512+k]) (k = bid-896)
// ---------------------------------------------------------------------------
__global__ __launch_bounds__(256)
void prep_xproj(const float* __restrict__ emb, const int* __restrict__ tv,
                const float* __restrict__ W_ih, const float* __restrict__ b_ih,
                float* __restrict__ xproj,
                const float* __restrict__ Whh, u32* __restrict__ Wt2,
                const float* __restrict__ Wd, float* __restrict__ Wdt,
                const float* __restrict__ W_out, u16* __restrict__ WoTb)
{
    const int bid = blockIdx.x;
    if (bid < 128) {
        gemm_tile_256(emb, tv, E_, W_ih, b_ih, xproj, 1024, E_, 1024,
                      (bid >> 4) * 64, (bid & 15) * 64);
    } else if (bid < 640) {
        int idx = (bid - 128) * 256 + threadIdx.x;   // 0..131071
        int kk = idx >> 10;                          // k-pair 0..127
        int r  = idx & 1023;
        float w0 = Whh[(size_t)r * 256 + 2 * kk];
        float w1 = Whh[(size_t)r * 256 + 2 * kk + 1];
        Wt2[idx] = pk2(w0, w1);
    } else if (bid < 896) {
        int idx = (bid - 640) * 256 + threadIdx.x;   // 0..65535
        int k = idx >> 8;
        int h = idx & 255;
        Wdt[idx] = Wd[(size_t)h * 256 + k];
    } else {
        int k = bid - 896;                           // 0..511
        #pragma unroll
        for (int j = 0; j < 4; j++) {
            int v = threadIdx.x + 256 * j;
            if (v < V_) WoTb[(size_t)k * V_ + v] = f2bf(W_out[(size_t)v * 512 + k]);
        }
    }
}

// ---------------------------------------------------------------------------
// Kernel 2: heterogeneous lstm + enc_t.
//   bid < 32 : LSTM scan v7 — f16 k-pair weights + v_dot2_f32_f16: one VALU op
//              per 2 MACs, full K per thread (no partial phase, one fewer
//              barrier), h-pairs packed via intra-wave shfl. u32 loads keep
//              the proven 256 B/wave pattern; unroll 2 caps in-flight loads.
//   bid >= 32: enc_t 128x128 tile (round-9 proven) on idle CUs.
// ---------------------------------------------------------------------------
__global__ __launch_bounds__(1024, 4)
void lstm_enct(const float* __restrict__ xproj,   // [T,B,1024]
               const u32*   __restrict__ Wt2,     // [128,1024] f16-pair
               const float* __restrict__ bhh,     // [1024]
               const float* __restrict__ h0, const float* __restrict__ c0,
               float* __restrict__ combined,      // [T,B,512] second half
               float* __restrict__ hT, float* __restrict__ cT,
               const float* __restrict__ enc_raw, // [8192,256]
               const float* __restrict__ We,      // [256,256]
               const float* __restrict__ be,
               float* __restrict__ enct)          // [8192,256]
{
    const int bid = blockIdx.x;
    const int tid = threadIdx.x;
    __shared__ float zs[1024], cs[256];
    __shared__ u32 hp[128];
    __shared__ float As2[32][132];
    __shared__ float Bs2[32][132];

    if (bid < 32) {
        const int b = bid;
        const int r = tid;
        if (tid < 256) {
            float h0v = h0[b * 256 + tid];
            cs[tid] = c0[b * 256 + tid];
            float hpart = __shfl_xor(h0v, 1, 64);
            if (!(tid & 1)) hp[tid >> 1] = pk2(h0v, hpart);
        }
        const float bh = bhh[r];
        const u32* wp = Wt2 + r;
        __syncthreads();

        for (int t = 0; t < T_; t++) {
            float xp = xproj[((size_t)t * B_ + b) * 1024 + r];
            float acc = 0.0f;
            const uint4* hp4 = (const uint4*)hp;
            #pragma unroll 2
            for (int i = 0; i < 32; i++) {
                uint4 hv = hp4[i];                       // 4 k-pairs, broadcast
                u32 w0 = wp[(size_t)(4 * i + 0) * 1024];
                u32 w1 = wp[(size_t)(4 * i + 1) * 1024];
                u32 w2 = wp[(size_t)(4 * i + 2) * 1024];
                u32 w3 = wp[(size_t)(4 * i + 3) * 1024];
                acc = dot2f16(w0, hv.x, acc);
                acc = dot2f16(w1, hv.y, acc);
                acc = dot2f16(w2, hv.z, acc);
                acc = dot2f16(w3, hv.w, acc);
            }
            zs[r] = xp + bh + acc;
            __syncthreads();

            if (tid < 256) {
                float ig = fast_sigm(zs[tid]);
                float fg = fast_sigm(zs[256 + tid]);
                float gg = fast_tanh(zs[512 + tid]);
                float og = fast_sigm(zs[768 + tid]);
                float c = fg * cs[tid] + ig * gg;
                float h = og * fast_tanh(c);
                cs[tid] = c;
                combined[((size_t)t * B_ + b) * 512 + 256 + tid] = h;
                if (t == T_ - 1) {
                    hT[b * 256 + tid] = h;
                    cT[b * 256 + tid] = c;
                }
                float hpart = __shfl_xor(h, 1, 64);
                if (!(tid & 1)) hp[tid >> 1] = pk2(h, hpart);
            }
            __syncthreads();
        }
    } else {
        const int tile = bid - 32;
        const int bm = (tile >> 1) * 128;
        const int bn = (tile & 1) * 128;
        const int tx = tid & 31, ty = tid >> 5;
        const int lr = tid >> 3;
        const int lk = (tid & 7) * 4;

        const float* Ap = enc_raw + (size_t)(bm + lr) * 256;
        const float* Bp = We + (size_t)(bn + lr) * 256;
        float acc[4][4] = {};

        for (int k0 = 0; k0 < 256; k0 += 32) {
            float4 a4 = *(const float4*)(Ap + k0 + lk);
            float4 b4 = *(const float4*)(Bp + k0 + lk);
            As2[lk + 0][lr] = a4.x; As2[lk + 1][lr] = a4.y;
            As2[lk + 2][lr] = a4.z; As2[lk + 3][lr] = a4.w;
            Bs2[lk + 0][lr] = b4.x; Bs2[lk + 1][lr] = b4.y;
            Bs2[lk + 2][lr] = b4.z; Bs2[lk + 3][lr] = b4.w;
            __syncthreads();
            #pragma unroll
            for (int kk = 0; kk < 32; kk++) {
                float4 a = *(const float4*)&As2[kk][ty * 4];
                float4 b = *(const float4*)&Bs2[kk][tx * 4];
                acc[0][0] += a.x*b.x; acc[0][1] += a.x*b.y; acc[0][2] += a.x*b.z; acc[0][3] += a.x*b.w;
                acc[1][0] += a.y*b.x; acc[1][1] += a.y*b.y; acc[1][2] += a.y*b.z; acc[1][3] += a.y*b.w;
                acc[2][0] += a.z*b.x; acc[2][1] += a.z*b.y; acc[2][2] += a.z*b.z; acc[2][3] += a.z*b.w;
                acc[3][0] += a.w*b.x; acc[3][1] += a.w*b.y; acc[3][2] += a.w*b.z; acc[3][3] += a.w*b.w;
            }
            __syncthreads();
        }
        #pragma unroll
        for (int i = 0; i < 4; i++) {
            int m = bm + ty * 4 + i;
            #pragma unroll
            for (int j = 0; j < 4; j++) {
                int n = bn + tx * 4 + j;
                enct[(size_t)m * 256 + n] = acc[i][j] + be[n];
            }
        }
    }
}

// ---------------------------------------------------------------------------
// Kernel 3: FUSED tail v2 (round-12 proven): 512 threads, XCD swizzle,
// bf16 WoT, dect/ctx split across thread halves, in-LDS logits + softmax.
// ---------------------------------------------------------------------------
__global__ __launch_bounds__(512)
void attn_logits(const float* __restrict__ enct,        // [S,B,H]
                 const float* __restrict__ combined_in, // [T,B,512] (2nd half)
                 const float* __restrict__ Wdt,         // [256,256] k-major
                 const float* __restrict__ bd,
                 const float* __restrict__ enc_raw,     // [S,B,H]
                 const float* __restrict__ wa, const float* __restrict__ ba,
                 const int* __restrict__ lens,
                 const u16* __restrict__ WoTb,          // [512,1000] bf16 k-major
                 const float* __restrict__ b_out,       // [1000]
                 float* __restrict__ ctx_out,           // [B,T,H] (d_out)
                 float* __restrict__ probs)             // [T,B,V] (d_out)
{
    const int bid = blockIdx.x;
    const int b = bid & 31;          // XCD swizzle: bid mod 8 == b mod 8
    const int t = bid >> 5;
    const int tid = threadIdx.x;
    const int wv = tid >> 6, lane = tid & 63;   // 8 waves
    __shared__ float ds[256], was[256], sc[256];
    __shared__ float crow[512];
    __shared__ float tmp2[512];
    __shared__ float lrow[1000];
    __shared__ float red[8], red2[8];

    if (tid < 256) {
        crow[256 + tid] = combined_in[((size_t)t * B_ + b) * 512 + 256 + tid];
        was[tid] = wa[tid];
    }
    const int len = lens[b];
    const float bav = ba[0];
    __syncthreads();

    {
        const int h  = tid & 255;
        const int k0 = (tid >> 8) * 128;
        float acc = 0.0f;
        const float* wp = Wdt + h;
        #pragma unroll 4
        for (int k = k0; k < k0 + 128; k++) acc += wp[(size_t)k * 256] * crow[256 + k];
        tmp2[tid] = acc;
    }
    __syncthreads();
    if (tid < 256) ds[tid] = bd[tid] + tmp2[tid] + tmp2[tid + 256];
    __syncthreads();

    for (int s = wv; s < len; s += 8) {
        const float* er = enct + ((size_t)s * B_ + b) * 256;
        float sum = 0.0f;
        #pragma unroll
        for (int j = 0; j < 4; j++) {
            int h = lane + 64 * j;
            sum += fast_tanh(er[h] + ds[h]) * was[h];
        }
        #pragma unroll
        for (int off = 32; off >= 1; off >>= 1) sum += __shfl_xor(sum, off, 64);
        if (lane == 0) sc[s] = sum + bav;
    }
    __syncthreads();

    float x = (tid < len) ? sc[tid] : -INFINITY;
    float m = x;
    #pragma unroll
    for (int off = 32; off >= 1; off >>= 1) m = fmaxf(m, __shfl_xor(m, off, 64));
    if (lane == 0) red[wv] = m;
    __syncthreads();
    m = red[0];
    #pragma unroll
    for (int i = 1; i < 8; i++) m = fmaxf(m, red[i]);
    float e = __expf(x - m);
    float ssum = e;
    #pragma unroll
    for (int off = 32; off >= 1; off >>= 1) ssum += __shfl_xor(ssum, off, 64);
    if (lane == 0) red2[wv] = ssum;
    __syncthreads();
    ssum = red2[0] + red2[1] + red2[2] + red2[3] + red2[4] + red2[5] + red2[6] + red2[7];
    if (tid < 256) sc[tid] = e / ssum;
    __syncthreads();

    {
        const int h  = tid & 255;
        const int sg = tid >> 8;
        const int mid = (len + 1) >> 1;
        const int s0 = sg ? mid : 0;
        const int s1 = sg ? len : mid;
        float cacc = 0.0f;
        const float* eb = enc_raw + (size_t)b * 256 + h;
        for (int s = s0; s < s1; s++) cacc += sc[s] * eb[(size_t)s * (B_ * H_)];
        tmp2[tid] = cacc;
    }
    __syncthreads();
    if (tid < 256) {
        float ctx = tmp2[tid] + tmp2[tid + 256];
        ctx_out[((size_t)b * T_ + t) * 256 + tid] = ctx;
        crow[tid] = ctx;
    }
    __syncthreads();

    if (tid < 500) {
        const int v0 = tid * 2;
        float a0 = b_out[v0], a1 = b_out[v0 + 1];
        const u32* wp = (const u32*)WoTb + tid;
        #pragma unroll 4
        for (int k = 0; k < 512; k++) {
            float c = crow[k];
            u32 w = wp[(size_t)k * 500];
            a0 += c * blo(w);
            a1 += c * bhi(w);
        }
        lrow[v0] = a0;
        lrow[v0 + 1] = a1;
    }
    __syncthreads();

    float v0v = -INFINITY, v1v = -INFINITY;
    if (tid < 500) { v0v = lrow[tid * 2]; v1v = lrow[tid * 2 + 1]; }
    float mx = fmaxf(v0v, v1v);
    #pragma unroll
    for (int off = 32; off >= 1; off >>= 1) mx = fmaxf(mx, __shfl_xor(mx, off, 64));
    if (lane == 0) red[wv] = mx;
    __syncthreads();
    mx = red[0];
    #pragma unroll
    for (int i = 1; i < 8; i++) mx = fmaxf(mx, red[i]);
    float e0 = __expf(v0v - mx), e1 = __expf(v1v - mx);
    float s2 = e0 + e1;
    #pragma unroll
    for (int off = 32; off >= 1; off >>= 1) s2 += __shfl_xor(s2, off, 64);
    if (lane == 0) red2[wv] = s2;
    __syncthreads();
    s2 = red2[0] + red2[1] + red2[2] + red2[3] + red2[4] + red2[5] + red2[6] + red2[7];
    float inv = 1.0f / s2;
    if (tid < 500) {
        float2 pv = make_float2(e0 * inv, e1 * inv);
        *(float2*)&probs[((size_t)t * B_ + b) * V_ + tid * 2] = pv;
    }
}

extern "C" void kernel_launch(void* const* d_in, const int* in_sizes, int n_in,
                              void* d_out, int out_size, void* d_ws, size_t ws_size,
                              hipStream_t stream) {
    const int*   tv       = (const int*)d_in[0];
    const float* h0       = (const float*)d_in[1];
    const float* c0       = (const float*)d_in[2];
    const float* enc_raw  = (const float*)d_in[3];
    const int*   lens     = (const int*)d_in[4];
    const float* emb      = (const float*)d_in[5];
    const float* W_ih     = (const float*)d_in[6];
    const float* W_hh     = (const float*)d_in[7];
    const float* b_ih     = (const float*)d_in[8];
    const float* b_hh     = (const float*)d_in[9];
    const float* We       = (const float*)d_in[10];
    const float* be       = (const float*)d_in[11];
    const float* Wd       = (const float*)d_in[12];
    const float* bd       = (const float*)d_in[13];
    const float* wa       = (const float*)d_in[14];
    const float* ba       = (const float*)d_in[15];
    const float* W_out    = (const float*)d_in[16];
    const float* b_out    = (const float*)d_in[17];

    // workspace layout (fp32 words; proven 14.63 MB footprint)
    float* ws       = (float*)d_ws;
    float* enct     = ws;                       // [8192,256]  2,097,152
    float* xproj    = ws + 2097152;             // [512,1024]    524,288
    float* Wdt      = ws + 2621440;             // [256,256]      65,536
    u16*   WoTb     = (u16*)(ws + 2752512);     // [512,1000] bf16
    float* combined = ws + 3264512;             // [512,512]     262,144
    u32*   Wt2      = (u32*)(ws + 3526656);     // [128,1024] f16-pair = 131,072 u32

    // d_out layout (fp32): probs [T,B,V], hT, cT, ctx [B,T,H]
    float* out      = (float*)d_out;
    float* probs    = out;
    float* hT       = out + 512000;
    float* cT       = out + 520192;
    float* ctx_out  = out + 528384;

    // 1) xproj GEMM + Whh(f16-pair)/Wd/W_out transposes
    prep_xproj<<<1408, 256, 0, stream>>>(emb, tv, W_ih, b_ih, xproj,
                                         W_hh, Wt2, Wd, Wdt, W_out, WoTb);
    // 2) LSTM v7 (dot2-f16) + enc_t GEMM
    lstm_enct<<<160, 1024, 0, stream>>>(xproj, Wt2, b_hh, h0, c0, combined, hT, cT,
                                        enc_raw, We, be, enct);
    // 3) fused attention + logits + vocab softmax
    attn_logits<<<512, 512, 0, stream>>>(enct, combined, Wdt, bd, enc_raw,
                                         wa, ba, lens, WoTb, b_out, ctx_out, probs);
}